// Round 13
// baseline (526.179 us; speedup 1.0000x reference)
//
#include <hip/hip_runtime.h>
#include <hip/hip_bf16.h>
#include <math.h>

#define BATCH 8
#define SQL 4096
#define SKL 4096
#define DIM 256
#define KVB 64

typedef __attribute__((ext_vector_type(8))) short short8;
typedef __attribute__((ext_vector_type(4))) float f32x4;
typedef __attribute__((ext_vector_type(4))) float floatx4;

typedef __attribute__((address_space(3))) unsigned int lds_uint;
typedef __attribute__((address_space(1))) unsigned int glob_uint;

__device__ __forceinline__ void gl_lds16(const void* g, void* l) {
  __builtin_amdgcn_global_load_lds((const glob_uint*)g, (lds_uint*)l, 16, 0, 0);
}

__device__ __forceinline__ short f2bf(float f) {
  union { float f; unsigned u; } x; x.f = f;
  unsigned r = x.u + 0x7fffu + ((x.u >> 16) & 1u);
  return (short)(r >> 16);
}

// Kt rows 512B / Vt rows 128B / Pl rows 128B: slot ^= row&7 (2-way residue, ~free)
__device__ __forceinline__ int swz(int row) { return (row & 7) << 4; }

// max-reduce across a 16-lane DPP row (our lr-group), pure VALU, bit-exact
__device__ __forceinline__ float dpp_max16(float v) {
  float t;
  t = __int_as_float(__builtin_amdgcn_mov_dpp(__float_as_int(v), 0xB1, 0xF, 0xF, true));  // quad_perm xor1
  v = fmaxf(v, t);
  t = __int_as_float(__builtin_amdgcn_mov_dpp(__float_as_int(v), 0x4E, 0xF, 0xF, true));  // quad_perm xor2
  v = fmaxf(v, t);
  t = __int_as_float(__builtin_amdgcn_mov_dpp(__float_as_int(v), 0x124, 0xF, 0xF, true)); // row_ror:4
  v = fmaxf(v, t);
  t = __int_as_float(__builtin_amdgcn_mov_dpp(__float_as_int(v), 0x128, 0xF, 0xF, true)); // row_ror:8
  v = fmaxf(v, t);
  return v;
}

// ---------- W fp32 -> bf16, once ----------
__global__ __launch_bounds__(256) void wcvt_kernel(
    const float* __restrict__ W0, const float* __restrict__ W1,
    const float* __restrict__ W2, short* __restrict__ out)
{
  const int m = blockIdx.x >> 5;
  const int i = ((blockIdx.x & 31) * 256 + threadIdx.x) * 8;
  const float* W = (m == 0) ? W0 : ((m == 1) ? W1 : W2);
  floatx4 a = *(const floatx4*)(W + i);
  floatx4 c = *(const floatx4*)(W + i + 4);
  short8 v;
  #pragma unroll
  for (int j = 0; j < 4; ++j) { v[j] = f2bf(a[j]); v[j+4] = f2bf(c[j]); }
  *(short8*)(out + (size_t)m * DIM * DIM + i) = v;
}

// ---------- projection: 32 m-rows/block; C = X.W^T + b, bf16 row-major out ----------
__global__ __launch_bounds__(256) void proj_kernel(
    const float* __restrict__ X, const short* __restrict__ Wb,
    const float* __restrict__ bias, short* __restrict__ out)
{
  const int lane = threadIdx.x & 63;
  const int wave = threadIdx.x >> 6;
  const int lr = lane & 15, hi = lane >> 4;
  const int m0 = blockIdx.x * 32;
  const int n0 = wave * 64;

  f32x4 acc0[4] = {(f32x4)0.f,(f32x4)0.f,(f32x4)0.f,(f32x4)0.f};
  f32x4 acc1[4] = {(f32x4)0.f,(f32x4)0.f,(f32x4)0.f,(f32x4)0.f};
  const float* xr0 = X + (size_t)(m0 + lr) * DIM;
  const float* xr1 = X + (size_t)(m0 + 16 + lr) * DIM;

  #pragma unroll
  for (int kk = 0; kk < 8; ++kk) {
    const int k8 = kk * 32 + hi * 8;
    floatx4 xa = *(const floatx4*)(xr0 + k8);
    floatx4 xb = *(const floatx4*)(xr0 + k8 + 4);
    floatx4 ya = *(const floatx4*)(xr1 + k8);
    floatx4 yb = *(const floatx4*)(xr1 + k8 + 4);
    short8 a0, a1;
    #pragma unroll
    for (int j = 0; j < 4; ++j) {
      a0[j] = f2bf(xa[j]); a0[j+4] = f2bf(xb[j]);
      a1[j] = f2bf(ya[j]); a1[j+4] = f2bf(yb[j]);
    }
    #pragma unroll
    for (int nb = 0; nb < 4; ++nb) {
      short8 bfr = *(const short8*)(Wb + (size_t)(n0 + nb*16 + lr) * DIM + k8);
      acc0[nb] = __builtin_amdgcn_mfma_f32_16x16x32_bf16(a0, bfr, acc0[nb], 0, 0, 0);
      acc1[nb] = __builtin_amdgcn_mfma_f32_16x16x32_bf16(a1, bfr, acc1[nb], 0, 0, 0);
    }
  }
  #pragma unroll
  for (int nb = 0; nb < 4; ++nb) {
    const int n = n0 + nb*16 + lr;
    const float bv = bias[n];
    #pragma unroll
    for (int r = 0; r < 4; ++r) {
      out[(size_t)(m0 + hi*4 + r) * DIM + n]      = f2bf(acc0[nb][r] + bv);
      out[(size_t)(m0 + 16 + hi*4 + r) * DIM + n] = f2bf(acc1[nb][r] + bv);
    }
  }
}

// ---------- V projection, output TRANSPOSED: outT[b][d][k], 32 rows/block ----------
__global__ __launch_bounds__(256) void projV_kernel(
    const float* __restrict__ X, const short* __restrict__ Wb,
    const float* __restrict__ bias, short* __restrict__ outT)
{
  __shared__ short tile[32][264];
  const int lane = threadIdx.x & 63;
  const int wave = threadIdx.x >> 6;
  const int lr = lane & 15, hi = lane >> 4;
  const int m0 = blockIdx.x * 32;
  const int n0 = wave * 64;

  f32x4 acc0[4] = {(f32x4)0.f,(f32x4)0.f,(f32x4)0.f,(f32x4)0.f};
  f32x4 acc1[4] = {(f32x4)0.f,(f32x4)0.f,(f32x4)0.f,(f32x4)0.f};
  const float* xr0 = X + (size_t)(m0 + lr) * DIM;
  const float* xr1 = X + (size_t)(m0 + 16 + lr) * DIM;

  #pragma unroll
  for (int kk = 0; kk < 8; ++kk) {
    const int k8 = kk * 32 + hi * 8;
    floatx4 xa = *(const floatx4*)(xr0 + k8);
    floatx4 xb = *(const floatx4*)(xr0 + k8 + 4);
    floatx4 ya = *(const floatx4*)(xr1 + k8);
    floatx4 yb = *(const floatx4*)(xr1 + k8 + 4);
    short8 a0, a1;
    #pragma unroll
    for (int j = 0; j < 4; ++j) {
      a0[j] = f2bf(xa[j]); a0[j+4] = f2bf(xb[j]);
      a1[j] = f2bf(ya[j]); a1[j+4] = f2bf(yb[j]);
    }
    #pragma unroll
    for (int nb = 0; nb < 4; ++nb) {
      short8 bfr = *(const short8*)(Wb + (size_t)(n0 + nb*16 + lr) * DIM + k8);
      acc0[nb] = __builtin_amdgcn_mfma_f32_16x16x32_bf16(a0, bfr, acc0[nb], 0, 0, 0);
      acc1[nb] = __builtin_amdgcn_mfma_f32_16x16x32_bf16(a1, bfr, acc1[nb], 0, 0, 0);
    }
  }
  #pragma unroll
  for (int nb = 0; nb < 4; ++nb) {
    const int n = n0 + nb*16 + lr;
    const float bv = bias[n];
    #pragma unroll
    for (int r = 0; r < 4; ++r) {
      tile[hi*4 + r][n]      = f2bf(acc0[nb][r] + bv);
      tile[16 + hi*4 + r][n] = f2bf(acc1[nb][r] + bv);
    }
  }
  __syncthreads();
  const int t = threadIdx.x;
  short8 v0, v1, v2, v3;
  #pragma unroll
  for (int k = 0; k < 8; ++k) {
    v0[k] = tile[k][t]; v1[k] = tile[k+8][t];
    v2[k] = tile[k+16][t]; v3[k] = tile[k+24][t];
  }
  const int b  = m0 >> 12;
  const int k0 = m0 & (SKL - 1);
  short* p = outT + (size_t)b * DIM * SKL + (size_t)t * SKL + k0;
  *(short8*)(p)      = v0;
  *(short8*)(p + 8)  = v1;
  *(short8*)(p + 16) = v2;
  *(short8*)(p + 24) = v3;
}

// ---------- flash attention: 8 waves (512 thr), 32 q/wave, KVB=64, dbuf, split-K ----------
// Every Kt/Vt b128 read feeds 2 MFMAs (2 resident Q frags / 2 accumulators).
// KH=2: halves write unnormalized partials + (m,l).  KH=1: full KV, direct out.
template<int KH>
__global__ __launch_bounds__(512, 2) void attn_kernel(
    const short* __restrict__ Qb, const short* __restrict__ Kb,
    const short* __restrict__ VtG, float* __restrict__ out,
    float* __restrict__ Opart, float2* __restrict__ ml)
{
  __shared__ alignas(16) short Kt[2][64][256];   // 64 KB, 512B rows, XOR swz
  __shared__ alignas(16) short Vt[2][256][64];   // 64 KB, 128B rows, XOR swz
  __shared__ alignas(16) short Pl[8][32][64];    // 32 KB per-wave P, 128B rows, XOR swz

  const int tid  = threadIdx.x;
  const int lane = tid & 63;
  const int wave = tid >> 6;                     // 0..7
  const int lr = lane & 15, hi = lane >> 4;

  const int b     = blockIdx.x & 7;              // batch -> XCD pinning
  const int kh    = (KH == 2) ? ((blockIdx.x >> 3) & 1) : 0;
  const int qtile = blockIdx.x >> ((KH == 2) ? 4 : 3);
  const int q0w   = qtile * 256 + wave * 32;
  const int kvbase = kh * (SKL / KH);
  const int NITER  = (SKL / KH) / KVB;

  const short* Qp = Qb  + ((size_t)b * SQL + q0w) * DIM;
  const short* Kp = Kb  + (size_t)b * SKL * DIM;
  const short* Vp = VtG + (size_t)b * DIM * SKL;

  short8 qf0[8], qf1[8];
  #pragma unroll
  for (int kk = 0; kk < 8; ++kk) {
    qf0[kk] = *(const short8*)(Qp + (size_t)lr        * DIM + kk*32 + hi*8);
    qf1[kk] = *(const short8*)(Qp + (size_t)(16 + lr) * DIM + kk*32 + hi*8);
  }

  f32x4 o0[16], o1[16];
  #pragma unroll
  for (int i = 0; i < 16; ++i) { o0[i] = (f32x4)0.f; o1[i] = (f32x4)0.f; }
  float mr0[4]   = {-3.0e38f,-3.0e38f,-3.0e38f,-3.0e38f};
  float mr1[4]   = {-3.0e38f,-3.0e38f,-3.0e38f,-3.0e38f};
  float lacc0[4] = {0.f,0.f,0.f,0.f};
  float lacc1[4] = {0.f,0.f,0.f,0.f};

  auto stage = [&](int buf, int kv) {
    #pragma unroll
    for (int i = 0; i < 4; ++i) {              // K: 64 rows x 512B
      const int row0 = wave*8 + i*2;
      const int row  = row0 + (lane >> 5);
      const int colb = ((lane & 31) * 16) ^ swz(row);
      gl_lds16((const char*)(Kp + (size_t)(kvbase + kv + row) * DIM) + colb,
               (void*)&Kt[buf][row0][0]);
    }
    #pragma unroll
    for (int i = 0; i < 4; ++i) {              // V^T: 256 rows x 128B
      const int d0 = wave*32 + i*8;
      const int d  = d0 + (lane >> 3);
      const int colb = ((lane & 7) * 16) ^ swz(d);
      gl_lds16((const char*)(Vp + (size_t)d * SKL + kvbase + kv) + colb,
               (void*)&Vt[buf][d0][0]);
    }
  };

  stage(0, 0);
  __syncthreads();
  int cur = 0;

  const char* plw = (const char*)&Pl[wave][0][0];

  for (int it = 0; it < NITER; ++it) {
    if (it + 1 < NITER) stage(cur ^ 1, (it + 1) * KVB);

    // ---- QK^T: S[32q][64k]; each kf read feeds 2 MFMAs ----
    const char* ktb = (const char*)&Kt[cur][0][0];
    f32x4 s0[4], s1[4];
    #pragma unroll
    for (int ks = 0; ks < 4; ++ks) { s0[ks] = (f32x4)0.f; s1[ks] = (f32x4)0.f; }
    __builtin_amdgcn_s_setprio(1);
    #pragma unroll
    for (int kk = 0; kk < 8; ++kk) {
      #pragma unroll
      for (int ks = 0; ks < 4; ++ks) {
        const int row = ks*16 + lr;
        short8 kf = *(const short8*)(ktb + row*512 + (((kk*64) + hi*16) ^ swz(row)));
        s0[ks] = __builtin_amdgcn_mfma_f32_16x16x32_bf16(qf0[kk], kf, s0[ks], 0, 0, 0);
        s1[ks] = __builtin_amdgcn_mfma_f32_16x16x32_bf16(qf1[kk], kf, s1[ks], 0, 0, 0);
      }
    }
    __builtin_amdgcn_s_setprio(0);

    // ---- EXACT online softmax, DPP max-reduce (R11-frozen numerics) ----
    #pragma unroll
    for (int r = 0; r < 4; ++r) {
      {
        float mx = dpp_max16(fmaxf(fmaxf(s0[0][r], s0[1][r]), fmaxf(s0[2][r], s0[3][r])));
        if (mx > mr0[r]) {
          const float sc = __expf(mr0[r] - mx);
          mr0[r] = mx;
          lacc0[r] *= sc;
          #pragma unroll
          for (int dt = 0; dt < 16; ++dt) o0[dt][r] *= sc;
        }
        const int row = hi*4 + r;
        #pragma unroll
        for (int ks = 0; ks < 4; ++ks) {
          const float p = __expf(s0[ks][r] - mr0[r]);
          lacc0[r] += p;
          *(short*)(plw + row*128 + ((2*(ks*16 + lr)) ^ swz(row))) = f2bf(p);
        }
      }
      {
        float mx = dpp_max16(fmaxf(fmaxf(s1[0][r], s1[1][r]), fmaxf(s1[2][r], s1[3][r])));
        if (mx > mr1[r]) {
          const float sc = __expf(mr1[r] - mx);
          mr1[r] = mx;
          lacc1[r] *= sc;
          #pragma unroll
          for (int dt = 0; dt < 16; ++dt) o1[dt][r] *= sc;
        }
        const int row = 16 + hi*4 + r;
        #pragma unroll
        for (int ks = 0; ks < 4; ++ks) {
          const float p = __expf(s1[ks][r] - mr1[r]);
          lacc1[r] += p;
          *(short*)(plw + row*128 + ((2*(ks*16 + lr)) ^ swz(row))) = f2bf(p);
        }
      }
    }

    // ---- PV: O[32q][256d] += P[32q][64k] . V[64k][256d]; each vf read feeds 2 MFMAs ----
    const char* vtb = (const char*)&Vt[cur][0][0];
    short8 pa0[2], pa1[2];
    #pragma unroll
    for (int kh2 = 0; kh2 < 2; ++kh2) {
      const int rowA = lr, rowB = 16 + lr;
      pa0[kh2] = *(const short8*)(plw + rowA*128 + ((kh2*64 + hi*16) ^ swz(rowA)));
      pa1[kh2] = *(const short8*)(plw + rowB*128 + ((kh2*64 + hi*16) ^ swz(rowB)));
    }
    __builtin_amdgcn_s_setprio(1);
    #pragma unroll
    for (int dt = 0; dt < 16; ++dt) {
      #pragma unroll
      for (int kh2 = 0; kh2 < 2; ++kh2) {
        const int d = dt*16 + lr;
        short8 vf = *(const short8*)(vtb + d*128 + ((kh2*64 + hi*16) ^ swz(d)));
        o0[dt] = __builtin_amdgcn_mfma_f32_16x16x32_bf16(pa0[kh2], vf, o0[dt], 0, 0, 0);
        o1[dt] = __builtin_amdgcn_mfma_f32_16x16x32_bf16(pa1[kh2], vf, o1[dt], 0, 0, 0);
      }
    }
    __builtin_amdgcn_s_setprio(0);

    __syncthreads();
    cur ^= 1;
  }

  // ---- epilogue: cross-lane reduce of l ----
  float ls0[4], ls1[4];
  #pragma unroll
  for (int r = 0; r < 4; ++r) { ls0[r] = lacc0[r]; ls1[r] = lacc1[r]; }
  #pragma unroll
  for (int off = 8; off >= 1; off >>= 1)
    #pragma unroll
    for (int r = 0; r < 4; ++r) {
      ls0[r] += __shfl_xor(ls0[r], off, 64);
      ls1[r] += __shfl_xor(ls1[r], off, 64);
    }

  if (KH == 1) {
    float* op = out + ((size_t)b * SQL + q0w) * DIM;
    #pragma unroll
    for (int r = 0; r < 4; ++r) {
      const float i0 = 1.0f / ls0[r];
      const float i1 = 1.0f / ls1[r];
      #pragma unroll
      for (int dt = 0; dt < 16; ++dt) {
        op[(size_t)(hi*4 + r) * DIM + dt*16 + lr]      = o0[dt][r] * i0;
        op[(size_t)(16 + hi*4 + r) * DIM + dt*16 + lr] = o1[dt][r] * i1;
      }
    }
  } else {
    const size_t BS = (size_t)BATCH * SQL;
    float* op = Opart + ((size_t)kh * BS + (size_t)b * SQL + q0w) * DIM;
    #pragma unroll
    for (int r = 0; r < 4; ++r) {
      #pragma unroll
      for (int dt = 0; dt < 16; ++dt) {
        op[(size_t)(hi*4 + r) * DIM + dt*16 + lr]      = o0[dt][r];
        op[(size_t)(16 + hi*4 + r) * DIM + dt*16 + lr] = o1[dt][r];
      }
      if (lr == 0) {
        float2 e0; e0.x = mr0[r]; e0.y = ls0[r];
        float2 e1; e1.x = mr1[r]; e1.y = ls1[r];
        ml[kh * BS + (size_t)b * SQL + q0w + hi*4 + r]      = e0;
        ml[kh * BS + (size_t)b * SQL + q0w + 16 + hi*4 + r] = e1;
      }
    }
  }
}

// ---------- merge the two split-K halves (max-weighted, R9-proven) ----------
__global__ __launch_bounds__(256) void merge_kernel(
    const float* __restrict__ Opart, const float2* __restrict__ ml,
    float* __restrict__ out)
{
  const size_t BS = (size_t)BATCH * SQL;
  const int t  = threadIdx.x;
  const size_t gq = (size_t)blockIdx.x * 4 + (t >> 6);
  const int dl = (t & 63) * 4;
  float2 e0 = ml[gq], e1 = ml[BS + gq];
  const float M  = fmaxf(e0.x, e1.x);
  const float w0 = __expf(e0.x - M);
  const float w1 = __expf(e1.x - M);
  const float inv = 1.0f / (e0.y * w0 + e1.y * w1);
  f32x4 a = *(const f32x4*)(Opart + gq * DIM + dl);
  f32x4 c = *(const f32x4*)(Opart + (BS + gq) * DIM + dl);
  f32x4 r;
  #pragma unroll
  for (int j = 0; j < 4; ++j) r[j] = (a[j] * w0 + c[j] * w1) * inv;
  *(f32x4*)(out + gq * DIM + dl) = r;
}

extern "C" void kernel_launch(void* const* d_in, const int* in_sizes, int n_in,
                              void* d_out, int out_size, void* d_ws, size_t ws_size,
                              hipStream_t stream) {
  const float* query  = (const float*)d_in[0];
  const float* keys   = (const float*)d_in[1];
  const float* values = (const float*)d_in[2];
  const float* Wq = (const float*)d_in[3];
  const float* bq = (const float*)d_in[4];
  const float* Wk = (const float*)d_in[5];
  const float* bk = (const float*)d_in[6];
  const float* Wv = (const float*)d_in[7];
  const float* bv = (const float*)d_in[8];
  float* out = (float*)d_out;

  const size_t elems = (size_t)BATCH * SQL * DIM;          // 8.39M
  const size_t BS    = (size_t)BATCH * SQL;                // 32768
  short* Qb  = (short*)d_ws;
  short* Kb  = Qb + elems;
  short* VtT = Kb + elems;

  const size_t wbytes    = (size_t)3 * DIM * DIM * sizeof(short);
  const size_t need_base = 3 * elems * sizeof(short) + wbytes;
  const size_t need_split = need_base + 2 * elems * sizeof(float) + 2 * BS * sizeof(float2);

  short* Wb;
  if (ws_size >= need_base) Wb = VtT + elems;
  else Wb = (short*)((char*)d_out + (size_t)out_size * sizeof(float) - wbytes);
  short* Wqb = Wb;
  short* Wkb = Wb + DIM * DIM;
  short* Wvb = Wb + 2 * DIM * DIM;

  dim3 blk(256, 1, 1);
  dim3 blk512(512, 1, 1);
  wcvt_kernel <<<dim3(96, 1, 1),           blk, 0, stream>>>(Wq, Wk, Wv, Wb);
  proj_kernel <<<dim3(BATCH*SQL/32, 1, 1), blk, 0, stream>>>(query,  Wqb, bq, Qb);
  proj_kernel <<<dim3(BATCH*SKL/32, 1, 1), blk, 0, stream>>>(keys,   Wkb, bk, Kb);
  projV_kernel<<<dim3(BATCH*SKL/32, 1, 1), blk, 0, stream>>>(values, Wvb, bv, VtT);

  if (ws_size >= need_split) {
    float*  Opart = (float*)((char*)d_ws + need_base);
    float2* ml    = (float2*)(Opart + 2 * elems);
    attn_kernel<2><<<dim3(256, 1, 1), blk512, 0, stream>>>(Qb, Kb, VtT, out, Opart, ml);
    merge_kernel  <<<dim3(BS/4, 1, 1), blk,    0, stream>>>(Opart, ml, out);
  } else {
    attn_kernel<1><<<dim3(128, 1, 1), blk512, 0, stream>>>(Qb, Kb, VtT, out, nullptr, nullptr);
  }
}

// Round 14
// 458.589 us; speedup vs baseline: 1.1474x; 1.1474x over previous
//
#include <hip/hip_runtime.h>
#include <hip/hip_bf16.h>
#include <math.h>

#define BATCH 8
#define SQL 4096
#define SKL 4096
#define DIM 256
#define KVB 64
#define NIT (SKL / KVB)

typedef __attribute__((ext_vector_type(8))) short short8;
typedef __attribute__((ext_vector_type(4))) float f32x4;
typedef __attribute__((ext_vector_type(4))) float floatx4;

typedef __attribute__((address_space(3))) unsigned int lds_uint;
typedef __attribute__((address_space(1))) unsigned int glob_uint;

__device__ __forceinline__ void gl_lds16(const void* g, void* l) {
  __builtin_amdgcn_global_load_lds((const glob_uint*)g, (lds_uint*)l, 16, 0, 0);
}

__device__ __forceinline__ short f2bf(float f) {
  union { float f; unsigned u; } x; x.f = f;
  unsigned r = x.u + 0x7fffu + ((x.u >> 16) & 1u);
  return (short)(r >> 16);
}

// Kt rows 512B / Vt rows 128B / Pl rows 128B: slot ^= row&7 (2-way residue, ~free)
__device__ __forceinline__ int swz(int row) { return (row & 7) << 4; }

// max-reduce across a 16-lane DPP row (our lr-group), pure VALU, bit-exact
__device__ __forceinline__ float dpp_max16(float v) {
  float t;
  t = __int_as_float(__builtin_amdgcn_mov_dpp(__float_as_int(v), 0xB1, 0xF, 0xF, true));  // quad_perm xor1
  v = fmaxf(v, t);
  t = __int_as_float(__builtin_amdgcn_mov_dpp(__float_as_int(v), 0x4E, 0xF, 0xF, true));  // quad_perm xor2
  v = fmaxf(v, t);
  t = __int_as_float(__builtin_amdgcn_mov_dpp(__float_as_int(v), 0x124, 0xF, 0xF, true)); // row_ror:4
  v = fmaxf(v, t);
  t = __int_as_float(__builtin_amdgcn_mov_dpp(__float_as_int(v), 0x128, 0xF, 0xF, true)); // row_ror:8
  v = fmaxf(v, t);
  return v;
}

// ---------- W fp32 -> bf16, once ----------
__global__ __launch_bounds__(256) void wcvt_kernel(
    const float* __restrict__ W0, const float* __restrict__ W1,
    const float* __restrict__ W2, short* __restrict__ out)
{
  const int m = blockIdx.x >> 5;
  const int i = ((blockIdx.x & 31) * 256 + threadIdx.x) * 8;
  const float* W = (m == 0) ? W0 : ((m == 1) ? W1 : W2);
  floatx4 a = *(const floatx4*)(W + i);
  floatx4 c = *(const floatx4*)(W + i + 4);
  short8 v;
  #pragma unroll
  for (int j = 0; j < 4; ++j) { v[j] = f2bf(a[j]); v[j+4] = f2bf(c[j]); }
  *(short8*)(out + (size_t)m * DIM * DIM + i) = v;
}

// ---------- projection: 32 m-rows/block; C = X.W^T + b, bf16 row-major out ----------
__global__ __launch_bounds__(256) void proj_kernel(
    const float* __restrict__ X, const short* __restrict__ Wb,
    const float* __restrict__ bias, short* __restrict__ out)
{
  const int lane = threadIdx.x & 63;
  const int wave = threadIdx.x >> 6;
  const int lr = lane & 15, hi = lane >> 4;
  const int m0 = blockIdx.x * 32;
  const int n0 = wave * 64;

  f32x4 acc0[4] = {(f32x4)0.f,(f32x4)0.f,(f32x4)0.f,(f32x4)0.f};
  f32x4 acc1[4] = {(f32x4)0.f,(f32x4)0.f,(f32x4)0.f,(f32x4)0.f};
  const float* xr0 = X + (size_t)(m0 + lr) * DIM;
  const float* xr1 = X + (size_t)(m0 + 16 + lr) * DIM;

  #pragma unroll
  for (int kk = 0; kk < 8; ++kk) {
    const int k8 = kk * 32 + hi * 8;
    floatx4 xa = *(const floatx4*)(xr0 + k8);
    floatx4 xb = *(const floatx4*)(xr0 + k8 + 4);
    floatx4 ya = *(const floatx4*)(xr1 + k8);
    floatx4 yb = *(const floatx4*)(xr1 + k8 + 4);
    short8 a0, a1;
    #pragma unroll
    for (int j = 0; j < 4; ++j) {
      a0[j] = f2bf(xa[j]); a0[j+4] = f2bf(xb[j]);
      a1[j] = f2bf(ya[j]); a1[j+4] = f2bf(yb[j]);
    }
    #pragma unroll
    for (int nb = 0; nb < 4; ++nb) {
      short8 bfr = *(const short8*)(Wb + (size_t)(n0 + nb*16 + lr) * DIM + k8);
      acc0[nb] = __builtin_amdgcn_mfma_f32_16x16x32_bf16(a0, bfr, acc0[nb], 0, 0, 0);
      acc1[nb] = __builtin_amdgcn_mfma_f32_16x16x32_bf16(a1, bfr, acc1[nb], 0, 0, 0);
    }
  }
  #pragma unroll
  for (int nb = 0; nb < 4; ++nb) {
    const int n = n0 + nb*16 + lr;
    const float bv = bias[n];
    #pragma unroll
    for (int r = 0; r < 4; ++r) {
      out[(size_t)(m0 + hi*4 + r) * DIM + n]      = f2bf(acc0[nb][r] + bv);
      out[(size_t)(m0 + 16 + hi*4 + r) * DIM + n] = f2bf(acc1[nb][r] + bv);
    }
  }
}

// ---------- V projection, output TRANSPOSED: outT[b][d][k], 32 rows/block ----------
__global__ __launch_bounds__(256) void projV_kernel(
    const float* __restrict__ X, const short* __restrict__ Wb,
    const float* __restrict__ bias, short* __restrict__ outT)
{
  __shared__ short tile[32][264];
  const int lane = threadIdx.x & 63;
  const int wave = threadIdx.x >> 6;
  const int lr = lane & 15, hi = lane >> 4;
  const int m0 = blockIdx.x * 32;
  const int n0 = wave * 64;

  f32x4 acc0[4] = {(f32x4)0.f,(f32x4)0.f,(f32x4)0.f,(f32x4)0.f};
  f32x4 acc1[4] = {(f32x4)0.f,(f32x4)0.f,(f32x4)0.f,(f32x4)0.f};
  const float* xr0 = X + (size_t)(m0 + lr) * DIM;
  const float* xr1 = X + (size_t)(m0 + 16 + lr) * DIM;

  #pragma unroll
  for (int kk = 0; kk < 8; ++kk) {
    const int k8 = kk * 32 + hi * 8;
    floatx4 xa = *(const floatx4*)(xr0 + k8);
    floatx4 xb = *(const floatx4*)(xr0 + k8 + 4);
    floatx4 ya = *(const floatx4*)(xr1 + k8);
    floatx4 yb = *(const floatx4*)(xr1 + k8 + 4);
    short8 a0, a1;
    #pragma unroll
    for (int j = 0; j < 4; ++j) {
      a0[j] = f2bf(xa[j]); a0[j+4] = f2bf(xb[j]);
      a1[j] = f2bf(ya[j]); a1[j+4] = f2bf(yb[j]);
    }
    #pragma unroll
    for (int nb = 0; nb < 4; ++nb) {
      short8 bfr = *(const short8*)(Wb + (size_t)(n0 + nb*16 + lr) * DIM + k8);
      acc0[nb] = __builtin_amdgcn_mfma_f32_16x16x32_bf16(a0, bfr, acc0[nb], 0, 0, 0);
      acc1[nb] = __builtin_amdgcn_mfma_f32_16x16x32_bf16(a1, bfr, acc1[nb], 0, 0, 0);
    }
  }
  #pragma unroll
  for (int nb = 0; nb < 4; ++nb) {
    const int n = n0 + nb*16 + lr;
    const float bv = bias[n];
    #pragma unroll
    for (int r = 0; r < 4; ++r) {
      tile[hi*4 + r][n]      = f2bf(acc0[nb][r] + bv);
      tile[16 + hi*4 + r][n] = f2bf(acc1[nb][r] + bv);
    }
  }
  __syncthreads();
  const int t = threadIdx.x;
  short8 v0, v1, v2, v3;
  #pragma unroll
  for (int k = 0; k < 8; ++k) {
    v0[k] = tile[k][t]; v1[k] = tile[k+8][t];
    v2[k] = tile[k+16][t]; v3[k] = tile[k+24][t];
  }
  const int b  = m0 >> 12;
  const int k0 = m0 & (SKL - 1);
  short* p = outT + (size_t)b * DIM * SKL + (size_t)t * SKL + k0;
  *(short8*)(p)      = v0;
  *(short8*)(p + 8)  = v1;
  *(short8*)(p + 16) = v2;
  *(short8*)(p + 24) = v3;
}

// ---------- flash attention: 8 waves (512 thr), 32 q/wave, d-HALF per block ----------
// Each block computes O[256q][128d] (dh selects d-half). QK^T+softmax run redundantly
// in both d-half blocks (bitwise identical) -> no merge. o = 64 regs/wave (fits 2/SIMD).
__global__ __launch_bounds__(512, 2) void attn_kernel(
    const short* __restrict__ Qb, const short* __restrict__ Kb,
    const short* __restrict__ VtG, float* __restrict__ out)
{
  __shared__ alignas(16) short Kt[2][64][256];   // 64 KB, 512B rows, XOR swz
  __shared__ alignas(16) short Vt[2][128][64];   // 32 KB (d-half), 128B rows, XOR swz
  __shared__ alignas(16) short Pl[8][32][64];    // 32 KB per-wave P, 128B rows, XOR swz

  const int tid  = threadIdx.x;
  const int lane = tid & 63;
  const int wave = tid >> 6;                     // 0..7
  const int lr = lane & 15, hi = lane >> 4;

  const int b     = blockIdx.x & 7;              // batch -> XCD pinning (grid=256)
  const int dh    = (blockIdx.x >> 3) & 1;       // d-half 0/1
  const int qtile = blockIdx.x >> 4;             // 0..15
  const int q0w   = qtile * 256 + wave * 32;

  const short* Qp = Qb  + ((size_t)b * SQL + q0w) * DIM;
  const short* Kp = Kb  + (size_t)b * SKL * DIM;
  const short* Vp = VtG + (size_t)b * DIM * SKL + (size_t)dh * 128 * SKL;

  short8 qf0[8], qf1[8];
  #pragma unroll
  for (int kk = 0; kk < 8; ++kk) {
    qf0[kk] = *(const short8*)(Qp + (size_t)lr        * DIM + kk*32 + hi*8);
    qf1[kk] = *(const short8*)(Qp + (size_t)(16 + lr) * DIM + kk*32 + hi*8);
  }

  f32x4 o0[8], o1[8];                            // 32q x 128d -> 64 regs total
  #pragma unroll
  for (int i = 0; i < 8; ++i) { o0[i] = (f32x4)0.f; o1[i] = (f32x4)0.f; }
  float mr0[4]   = {-3.0e38f,-3.0e38f,-3.0e38f,-3.0e38f};
  float mr1[4]   = {-3.0e38f,-3.0e38f,-3.0e38f,-3.0e38f};
  float lacc0[4] = {0.f,0.f,0.f,0.f};
  float lacc1[4] = {0.f,0.f,0.f,0.f};

  auto stage = [&](int buf, int kv) {
    #pragma unroll
    for (int i = 0; i < 4; ++i) {              // K: 64 rows x 512B
      const int row0 = wave*8 + i*2;
      const int row  = row0 + (lane >> 5);
      const int colb = ((lane & 31) * 16) ^ swz(row);
      gl_lds16((const char*)(Kp + (size_t)(kv + row) * DIM) + colb, (void*)&Kt[buf][row0][0]);
    }
    #pragma unroll
    for (int i = 0; i < 2; ++i) {              // V^T half: 128 rows x 128B
      const int d0 = wave*16 + i*8;
      const int d  = d0 + (lane >> 3);
      const int colb = ((lane & 7) * 16) ^ swz(d);
      gl_lds16((const char*)(Vp + (size_t)d * SKL + kv) + colb, (void*)&Vt[buf][d0][0]);
    }
  };

  stage(0, 0);
  __syncthreads();
  int cur = 0;

  const char* plw = (const char*)&Pl[wave][0][0];

  for (int it = 0; it < NIT; ++it) {
    if (it + 1 < NIT) stage(cur ^ 1, (it + 1) * KVB);

    // ---- QK^T: S[32q][64k]; each kf read feeds 2 MFMAs ----
    const char* ktb = (const char*)&Kt[cur][0][0];
    f32x4 s0[4], s1[4];
    #pragma unroll
    for (int ks = 0; ks < 4; ++ks) { s0[ks] = (f32x4)0.f; s1[ks] = (f32x4)0.f; }
    __builtin_amdgcn_s_setprio(1);
    #pragma unroll
    for (int kk = 0; kk < 8; ++kk) {
      #pragma unroll
      for (int ks = 0; ks < 4; ++ks) {
        const int row = ks*16 + lr;
        short8 kf = *(const short8*)(ktb + row*512 + (((kk*64) + hi*16) ^ swz(row)));
        s0[ks] = __builtin_amdgcn_mfma_f32_16x16x32_bf16(qf0[kk], kf, s0[ks], 0, 0, 0);
        s1[ks] = __builtin_amdgcn_mfma_f32_16x16x32_bf16(qf1[kk], kf, s1[ks], 0, 0, 0);
      }
    }
    __builtin_amdgcn_s_setprio(0);

    // ---- EXACT online softmax (R11-frozen numerics), DPP max-reduce ----
    #pragma unroll
    for (int r = 0; r < 4; ++r) {
      {
        float mx = dpp_max16(fmaxf(fmaxf(s0[0][r], s0[1][r]), fmaxf(s0[2][r], s0[3][r])));
        if (mx > mr0[r]) {
          const float sc = __expf(mr0[r] - mx);
          mr0[r] = mx;
          lacc0[r] *= sc;
          #pragma unroll
          for (int dt = 0; dt < 8; ++dt) o0[dt][r] *= sc;
        }
        const int row = hi*4 + r;
        #pragma unroll
        for (int ks = 0; ks < 4; ++ks) {
          const float p = __expf(s0[ks][r] - mr0[r]);
          lacc0[r] += p;
          *(short*)(plw + row*128 + ((2*(ks*16 + lr)) ^ swz(row))) = f2bf(p);
        }
      }
      {
        float mx = dpp_max16(fmaxf(fmaxf(s1[0][r], s1[1][r]), fmaxf(s1[2][r], s1[3][r])));
        if (mx > mr1[r]) {
          const float sc = __expf(mr1[r] - mx);
          mr1[r] = mx;
          lacc1[r] *= sc;
          #pragma unroll
          for (int dt = 0; dt < 8; ++dt) o1[dt][r] *= sc;
        }
        const int row = 16 + hi*4 + r;
        #pragma unroll
        for (int ks = 0; ks < 4; ++ks) {
          const float p = __expf(s1[ks][r] - mr1[r]);
          lacc1[r] += p;
          *(short*)(plw + row*128 + ((2*(ks*16 + lr)) ^ swz(row))) = f2bf(p);
        }
      }
    }

    // ---- PV: O[32q][128d] += P[32q][64k] . V[64k][128d]; each vf feeds 2 MFMAs ----
    const char* vtb = (const char*)&Vt[cur][0][0];
    short8 pa0[2], pa1[2];
    #pragma unroll
    for (int kh = 0; kh < 2; ++kh) {
      const int rowA = lr, rowB = 16 + lr;
      pa0[kh] = *(const short8*)(plw + rowA*128 + ((kh*64 + hi*16) ^ swz(rowA)));
      pa1[kh] = *(const short8*)(plw + rowB*128 + ((kh*64 + hi*16) ^ swz(rowB)));
    }
    __builtin_amdgcn_s_setprio(1);
    #pragma unroll
    for (int dt = 0; dt < 8; ++dt) {
      #pragma unroll
      for (int kh = 0; kh < 2; ++kh) {
        const int d = dt*16 + lr;                // local row in Vt (0..127)
        short8 vf = *(const short8*)(vtb + d*128 + ((kh*64 + hi*16) ^ swz(d)));
        o0[dt] = __builtin_amdgcn_mfma_f32_16x16x32_bf16(pa0[kh], vf, o0[dt], 0, 0, 0);
        o1[dt] = __builtin_amdgcn_mfma_f32_16x16x32_bf16(pa1[kh], vf, o1[dt], 0, 0, 0);
      }
    }
    __builtin_amdgcn_s_setprio(0);

    __syncthreads();
    cur ^= 1;
  }

  // ---- epilogue: cross-lane reduce of l, normalize, store this d-half ----
  float ls0[4], ls1[4];
  #pragma unroll
  for (int r = 0; r < 4; ++r) { ls0[r] = lacc0[r]; ls1[r] = lacc1[r]; }
  #pragma unroll
  for (int off = 8; off >= 1; off >>= 1)
    #pragma unroll
    for (int r = 0; r < 4; ++r) {
      ls0[r] += __shfl_xor(ls0[r], off, 64);
      ls1[r] += __shfl_xor(ls1[r], off, 64);
    }

  float* op = out + ((size_t)b * SQL + q0w) * DIM + dh * 128;
  #pragma unroll
  for (int r = 0; r < 4; ++r) {
    const float i0 = 1.0f / ls0[r];
    const float i1 = 1.0f / ls1[r];
    #pragma unroll
    for (int dt = 0; dt < 8; ++dt) {
      op[(size_t)(hi*4 + r) * DIM + dt*16 + lr]      = o0[dt][r] * i0;
      op[(size_t)(16 + hi*4 + r) * DIM + dt*16 + lr] = o1[dt][r] * i1;
    }
  }
}

extern "C" void kernel_launch(void* const* d_in, const int* in_sizes, int n_in,
                              void* d_out, int out_size, void* d_ws, size_t ws_size,
                              hipStream_t stream) {
  const float* query  = (const float*)d_in[0];
  const float* keys   = (const float*)d_in[1];
  const float* values = (const float*)d_in[2];
  const float* Wq = (const float*)d_in[3];
  const float* bq = (const float*)d_in[4];
  const float* Wk = (const float*)d_in[5];
  const float* bk = (const float*)d_in[6];
  const float* Wv = (const float*)d_in[7];
  const float* bv = (const float*)d_in[8];
  float* out = (float*)d_out;

  const size_t elems = (size_t)BATCH * SQL * DIM;
  short* Qb  = (short*)d_ws;
  short* Kb  = Qb + elems;
  short* VtT = Kb + elems;

  const size_t wbytes    = (size_t)3 * DIM * DIM * sizeof(short);
  const size_t need_base = 3 * elems * sizeof(short) + wbytes;
  short* Wb;
  if (ws_size >= need_base) Wb = VtT + elems;
  else Wb = (short*)((char*)d_out + (size_t)out_size * sizeof(float) - wbytes);
  short* Wqb = Wb;
  short* Wkb = Wb + DIM * DIM;
  short* Wvb = Wb + 2 * DIM * DIM;

  dim3 blk(256, 1, 1);
  dim3 blk512(512, 1, 1);
  wcvt_kernel <<<dim3(96, 1, 1),           blk, 0, stream>>>(Wq, Wk, Wv, Wb);
  proj_kernel <<<dim3(BATCH*SQL/32, 1, 1), blk, 0, stream>>>(query,  Wqb, bq, Qb);
  proj_kernel <<<dim3(BATCH*SKL/32, 1, 1), blk, 0, stream>>>(keys,   Wkb, bk, Kb);
  projV_kernel<<<dim3(BATCH*SKL/32, 1, 1), blk, 0, stream>>>(values, Wvb, bv, VtT);
  // grid 256 = 8 batch x 2 d-half x 16 q-tiles (256 q each)
  attn_kernel <<<dim3(256, 1, 1), blk512, 0, stream>>>(Qb, Kb, VtT, out);
}

// Round 15
// 322.554 us; speedup vs baseline: 1.6313x; 1.4217x over previous
//
#include <hip/hip_runtime.h>
#include <hip/hip_bf16.h>
#include <math.h>

#define BATCH 8
#define SQL 4096
#define SKL 4096
#define DIM 256
#define KVB 64
#define NIT (SKL / KVB)

typedef __attribute__((ext_vector_type(8))) short short8;
typedef __attribute__((ext_vector_type(4))) float f32x4;
typedef __attribute__((ext_vector_type(4))) float floatx4;

typedef __attribute__((address_space(3))) unsigned int lds_uint;
typedef __attribute__((address_space(1))) unsigned int glob_uint;

__device__ __forceinline__ void gl_lds16(const void* g, void* l) {
  __builtin_amdgcn_global_load_lds((const glob_uint*)g, (lds_uint*)l, 16, 0, 0);
}

__device__ __forceinline__ short f2bf(float f) {
  union { float f; unsigned u; } x; x.f = f;
  unsigned r = x.u + 0x7fffu + ((x.u >> 16) & 1u);
  return (short)(r >> 16);
}

// Kt rows 512B / Vt rows 128B / Pl rows 128B: slot ^= row&7 (2-way residue)
__device__ __forceinline__ int swz(int row) { return (row & 7) << 4; }

// max-reduce across a 16-lane DPP row, pure VALU, bit-exact (R12-proven)
__device__ __forceinline__ float dpp_max16(float v) {
  float t;
  t = __int_as_float(__builtin_amdgcn_mov_dpp(__float_as_int(v), 0xB1, 0xF, 0xF, true));
  v = fmaxf(v, t);
  t = __int_as_float(__builtin_amdgcn_mov_dpp(__float_as_int(v), 0x4E, 0xF, 0xF, true));
  v = fmaxf(v, t);
  t = __int_as_float(__builtin_amdgcn_mov_dpp(__float_as_int(v), 0x124, 0xF, 0xF, true));
  v = fmaxf(v, t);
  t = __int_as_float(__builtin_amdgcn_mov_dpp(__float_as_int(v), 0x128, 0xF, 0xF, true));
  v = fmaxf(v, t);
  return v;
}

// ---------- W fp32 -> bf16, once ----------
__global__ __launch_bounds__(256) void wcvt_kernel(
    const float* __restrict__ W0, const float* __restrict__ W1,
    const float* __restrict__ W2, short* __restrict__ out)
{
  const int m = blockIdx.x >> 5;
  const int i = ((blockIdx.x & 31) * 256 + threadIdx.x) * 8;
  const float* W = (m == 0) ? W0 : ((m == 1) ? W1 : W2);
  floatx4 a = *(const floatx4*)(W + i);
  floatx4 c = *(const floatx4*)(W + i + 4);
  short8 v;
  #pragma unroll
  for (int j = 0; j < 4; ++j) { v[j] = f2bf(a[j]); v[j+4] = f2bf(c[j]); }
  *(short8*)(out + (size_t)m * DIM * DIM + i) = v;
}

// ---------- projection: 32 m-rows/block; C = X.W^T + b, bf16 row-major out ----------
__global__ __launch_bounds__(256) void proj_kernel(
    const float* __restrict__ X, const short* __restrict__ Wb,
    const float* __restrict__ bias, short* __restrict__ out)
{
  const int lane = threadIdx.x & 63;
  const int wave = threadIdx.x >> 6;
  const int lr = lane & 15, hi = lane >> 4;
  const int m0 = blockIdx.x * 32;
  const int n0 = wave * 64;

  f32x4 acc0[4] = {(f32x4)0.f,(f32x4)0.f,(f32x4)0.f,(f32x4)0.f};
  f32x4 acc1[4] = {(f32x4)0.f,(f32x4)0.f,(f32x4)0.f,(f32x4)0.f};
  const float* xr0 = X + (size_t)(m0 + lr) * DIM;
  const float* xr1 = X + (size_t)(m0 + 16 + lr) * DIM;

  #pragma unroll
  for (int kk = 0; kk < 8; ++kk) {
    const int k8 = kk * 32 + hi * 8;
    floatx4 xa = *(const floatx4*)(xr0 + k8);
    floatx4 xb = *(const floatx4*)(xr0 + k8 + 4);
    floatx4 ya = *(const floatx4*)(xr1 + k8);
    floatx4 yb = *(const floatx4*)(xr1 + k8 + 4);
    short8 a0, a1;
    #pragma unroll
    for (int j = 0; j < 4; ++j) {
      a0[j] = f2bf(xa[j]); a0[j+4] = f2bf(xb[j]);
      a1[j] = f2bf(ya[j]); a1[j+4] = f2bf(yb[j]);
    }
    #pragma unroll
    for (int nb = 0; nb < 4; ++nb) {
      short8 bfr = *(const short8*)(Wb + (size_t)(n0 + nb*16 + lr) * DIM + k8);
      acc0[nb] = __builtin_amdgcn_mfma_f32_16x16x32_bf16(a0, bfr, acc0[nb], 0, 0, 0);
      acc1[nb] = __builtin_amdgcn_mfma_f32_16x16x32_bf16(a1, bfr, acc1[nb], 0, 0, 0);
    }
  }
  #pragma unroll
  for (int nb = 0; nb < 4; ++nb) {
    const int n = n0 + nb*16 + lr;
    const float bv = bias[n];
    #pragma unroll
    for (int r = 0; r < 4; ++r) {
      out[(size_t)(m0 + hi*4 + r) * DIM + n]      = f2bf(acc0[nb][r] + bv);
      out[(size_t)(m0 + 16 + hi*4 + r) * DIM + n] = f2bf(acc1[nb][r] + bv);
    }
  }
}

// ---------- V projection, output TRANSPOSED: outT[b][d][k], 32 rows/block ----------
__global__ __launch_bounds__(256) void projV_kernel(
    const float* __restrict__ X, const short* __restrict__ Wb,
    const float* __restrict__ bias, short* __restrict__ outT)
{
  __shared__ short tile[32][264];
  const int lane = threadIdx.x & 63;
  const int wave = threadIdx.x >> 6;
  const int lr = lane & 15, hi = lane >> 4;
  const int m0 = blockIdx.x * 32;
  const int n0 = wave * 64;

  f32x4 acc0[4] = {(f32x4)0.f,(f32x4)0.f,(f32x4)0.f,(f32x4)0.f};
  f32x4 acc1[4] = {(f32x4)0.f,(f32x4)0.f,(f32x4)0.f,(f32x4)0.f};
  const float* xr0 = X + (size_t)(m0 + lr) * DIM;
  const float* xr1 = X + (size_t)(m0 + 16 + lr) * DIM;

  #pragma unroll
  for (int kk = 0; kk < 8; ++kk) {
    const int k8 = kk * 32 + hi * 8;
    floatx4 xa = *(const floatx4*)(xr0 + k8);
    floatx4 xb = *(const floatx4*)(xr0 + k8 + 4);
    floatx4 ya = *(const floatx4*)(xr1 + k8);
    floatx4 yb = *(const floatx4*)(xr1 + k8 + 4);
    short8 a0, a1;
    #pragma unroll
    for (int j = 0; j < 4; ++j) {
      a0[j] = f2bf(xa[j]); a0[j+4] = f2bf(xb[j]);
      a1[j] = f2bf(ya[j]); a1[j+4] = f2bf(yb[j]);
    }
    #pragma unroll
    for (int nb = 0; nb < 4; ++nb) {
      short8 bfr = *(const short8*)(Wb + (size_t)(n0 + nb*16 + lr) * DIM + k8);
      acc0[nb] = __builtin_amdgcn_mfma_f32_16x16x32_bf16(a0, bfr, acc0[nb], 0, 0, 0);
      acc1[nb] = __builtin_amdgcn_mfma_f32_16x16x32_bf16(a1, bfr, acc1[nb], 0, 0, 0);
    }
  }
  #pragma unroll
  for (int nb = 0; nb < 4; ++nb) {
    const int n = n0 + nb*16 + lr;
    const float bv = bias[n];
    #pragma unroll
    for (int r = 0; r < 4; ++r) {
      tile[hi*4 + r][n]      = f2bf(acc0[nb][r] + bv);
      tile[16 + hi*4 + r][n] = f2bf(acc1[nb][r] + bv);
    }
  }
  __syncthreads();
  const int t = threadIdx.x;
  short8 v0, v1, v2, v3;
  #pragma unroll
  for (int k = 0; k < 8; ++k) {
    v0[k] = tile[k][t]; v1[k] = tile[k+8][t];
    v2[k] = tile[k+16][t]; v3[k] = tile[k+24][t];
  }
  const int b  = m0 >> 12;
  const int k0 = m0 & (SKL - 1);
  short* p = outT + (size_t)b * DIM * SKL + (size_t)t * SKL + k0;
  *(short8*)(p)      = v0;
  *(short8*)(p + 8)  = v1;
  *(short8*)(p + 16) = v2;
  *(short8*)(p + 24) = v3;
}

// ---------- flash attention: shared-P. 8 waves, block=128q. ----------
// Per wave: QK^T+softmax on 16q (own rows) -> shared P/sc; barrier;
// PV on a 32q x 128d quadrant reading shared P. Bitwise = R12 numerics.
__global__ __launch_bounds__(512, 2) void attn_kernel(
    const short* __restrict__ Qb, const short* __restrict__ Kb,
    const short* __restrict__ VtG, float* __restrict__ out)
{
  __shared__ alignas(16) short Kt[2][64][256];   // 64 KB, XOR swz
  __shared__ alignas(16) short Vt[2][256][64];   // 64 KB, XOR swz
  __shared__ alignas(16) short Pl[128][64];      // 16 KB shared P, XOR swz
  __shared__ float scs[128];                     // per-row rescale factor this iter
  __shared__ float lshare[128];                  // per-row l (epilogue)

  const int tid  = threadIdx.x;
  const int lane = tid & 63;
  const int wave = tid >> 6;                     // 0..7
  const int lr = lane & 15, hi = lane >> 4;

  const int b     = blockIdx.x & 7;              // batch -> XCD pinning (grid=256)
  const int qtile = blockIdx.x >> 3;             // 0..31
  const int q0b   = qtile * 128;                 // block q-base

  const int qk_q0 = wave * 16;                   // this wave's QK rows (local)
  const int pv_q0 = (wave & 3) * 32;             // this wave's PV rows (local)
  const int d0    = (wave >> 2) * 128;           // this wave's PV d-half

  const short* Qp = Qb  + ((size_t)b * SQL + q0b + qk_q0) * DIM;
  const short* Kp = Kb  + (size_t)b * SKL * DIM;
  const short* Vp = VtG + (size_t)b * DIM * SKL;

  short8 qf[8];
  #pragma unroll
  for (int kk = 0; kk < 8; ++kk)
    qf[kk] = *(const short8*)(Qp + (size_t)lr * DIM + kk*32 + hi*8);

  f32x4 o0[8], o1[8];                            // PV quadrant: 32q x 128d
  #pragma unroll
  for (int i = 0; i < 8; ++i) { o0[i] = (f32x4)0.f; o1[i] = (f32x4)0.f; }
  float mr[4]   = {-3.0e38f,-3.0e38f,-3.0e38f,-3.0e38f};
  float lacc[4] = {0.f,0.f,0.f,0.f};

  auto stage = [&](int buf, int kv) {
    #pragma unroll
    for (int i = 0; i < 4; ++i) {              // K: 64 rows x 512B
      const int row0 = wave*8 + i*2;
      const int row  = row0 + (lane >> 5);
      const int colb = ((lane & 31) * 16) ^ swz(row);
      gl_lds16((const char*)(Kp + (size_t)(kv + row) * DIM) + colb, (void*)&Kt[buf][row0][0]);
    }
    #pragma unroll
    for (int i = 0; i < 4; ++i) {              // V^T: 256 rows x 128B
      const int dd0 = wave*32 + i*8;
      const int d   = dd0 + (lane >> 3);
      const int colb = ((lane & 7) * 16) ^ swz(d);
      gl_lds16((const char*)(Vp + (size_t)d * SKL + kv) + colb, (void*)&Vt[buf][dd0][0]);
    }
  };

  stage(0, 0);
  __syncthreads();
  int cur = 0;

  const char* plB = (const char*)&Pl[0][0];

  for (int it = 0; it < NIT; ++it) {
    if (it + 1 < NIT) stage(cur ^ 1, (it + 1) * KVB);

    // ---- QK^T: S[16q][64k] for this wave's rows ----
    const char* ktb = (const char*)&Kt[cur][0][0];
    f32x4 s[4];
    #pragma unroll
    for (int ks = 0; ks < 4; ++ks) s[ks] = (f32x4)0.f;
    __builtin_amdgcn_s_setprio(1);
    #pragma unroll
    for (int kk = 0; kk < 8; ++kk) {
      #pragma unroll
      for (int ks = 0; ks < 4; ++ks) {
        const int row = ks*16 + lr;
        short8 kf = *(const short8*)(ktb + row*512 + (((kk*64) + hi*16) ^ swz(row)));
        s[ks] = __builtin_amdgcn_mfma_f32_16x16x32_bf16(qf[kk], kf, s[ks], 0, 0, 0);
      }
    }
    __builtin_amdgcn_s_setprio(0);

    // ---- EXACT online softmax (R12-frozen numerics), write P + sc ----
    #pragma unroll
    for (int r = 0; r < 4; ++r) {
      float mx = dpp_max16(fmaxf(fmaxf(s[0][r], s[1][r]), fmaxf(s[2][r], s[3][r])));
      float sc = 1.0f;
      if (mx > mr[r]) {
        sc = __expf(mr[r] - mx);                 // first iter: exp(-inf)=0
        mr[r] = mx;
        lacc[r] *= sc;
      }
      const int row = qk_q0 + hi*4 + r;          // global (block-local) P row
      if (lr == 0) scs[row] = sc;                // one lane per row
      #pragma unroll
      for (int ks = 0; ks < 4; ++ks) {
        const float p = __expf(s[ks][r] - mr[r]);   // <= 1
        lacc[r] += p;
        *(short*)(plB + row*128 + ((2*(ks*16 + lr)) ^ swz(row))) = f2bf(p);
      }
    }

    __syncthreads();   // P + sc visible to all waves (also drains staging loads)

    // ---- PV: this wave's 32q x 128d quadrant from shared P ----
    // rescale o with sc (sc==1.0 is bitwise identity)
    float sc0[4], sc1[4];
    #pragma unroll
    for (int r = 0; r < 4; ++r) {
      sc0[r] = scs[pv_q0 + hi*4 + r];
      sc1[r] = scs[pv_q0 + 16 + hi*4 + r];
    }
    #pragma unroll
    for (int dt = 0; dt < 8; ++dt)
      #pragma unroll
      for (int r = 0; r < 4; ++r) {
        o0[dt][r] *= sc0[r];
        o1[dt][r] *= sc1[r];
      }

    const char* vtb = (const char*)&Vt[cur][0][0];
    short8 pa0[2], pa1[2];
    #pragma unroll
    for (int kh = 0; kh < 2; ++kh) {
      const int rowA = pv_q0 + lr, rowB = pv_q0 + 16 + lr;
      pa0[kh] = *(const short8*)(plB + rowA*128 + ((kh*64 + hi*16) ^ swz(rowA)));
      pa1[kh] = *(const short8*)(plB + rowB*128 + ((kh*64 + hi*16) ^ swz(rowB)));
    }
    __builtin_amdgcn_s_setprio(1);
    #pragma unroll
    for (int dt = 0; dt < 8; ++dt) {
      #pragma unroll
      for (int kh = 0; kh < 2; ++kh) {
        const int d = d0 + dt*16 + lr;           // global d row in Vt
        short8 vf = *(const short8*)(vtb + d*128 + ((kh*64 + hi*16) ^ swz(d)));
        o0[dt] = __builtin_amdgcn_mfma_f32_16x16x32_bf16(pa0[kh], vf, o0[dt], 0, 0, 0);
        o1[dt] = __builtin_amdgcn_mfma_f32_16x16x32_bf16(pa1[kh], vf, o1[dt], 0, 0, 0);
      }
    }
    __builtin_amdgcn_s_setprio(0);

    __syncthreads();   // protect P/sc from next-iter overwrite; buf swap
    cur ^= 1;
  }

  // ---- epilogue: l tree (bitwise R12), share l, normalize quadrant ----
  float lsum[4];
  #pragma unroll
  for (int r = 0; r < 4; ++r) lsum[r] = lacc[r];
  #pragma unroll
  for (int off = 8; off >= 1; off >>= 1)
    #pragma unroll
    for (int r = 0; r < 4; ++r)
      lsum[r] += __shfl_xor(lsum[r], off, 64);
  if (lr == 0)
    #pragma unroll
    for (int r = 0; r < 4; ++r)
      lshare[qk_q0 + hi*4 + r] = lsum[r];
  __syncthreads();

  float* op = out + ((size_t)b * SQL + q0b + pv_q0) * DIM + d0;
  #pragma unroll
  for (int r = 0; r < 4; ++r) {
    const float i0 = 1.0f / lshare[pv_q0 + hi*4 + r];
    const float i1 = 1.0f / lshare[pv_q0 + 16 + hi*4 + r];
    #pragma unroll
    for (int dt = 0; dt < 8; ++dt) {
      op[(size_t)(hi*4 + r) * DIM + dt*16 + lr]      = o0[dt][r] * i0;
      op[(size_t)(16 + hi*4 + r) * DIM + dt*16 + lr] = o1[dt][r] * i1;
    }
  }
}

extern "C" void kernel_launch(void* const* d_in, const int* in_sizes, int n_in,
                              void* d_out, int out_size, void* d_ws, size_t ws_size,
                              hipStream_t stream) {
  const float* query  = (const float*)d_in[0];
  const float* keys   = (const float*)d_in[1];
  const float* values = (const float*)d_in[2];
  const float* Wq = (const float*)d_in[3];
  const float* bq = (const float*)d_in[4];
  const float* Wk = (const float*)d_in[5];
  const float* bk = (const float*)d_in[6];
  const float* Wv = (const float*)d_in[7];
  const float* bv = (const float*)d_in[8];
  float* out = (float*)d_out;

  const size_t elems = (size_t)BATCH * SQL * DIM;
  short* Qb  = (short*)d_ws;
  short* Kb  = Qb + elems;
  short* VtT = Kb + elems;

  const size_t wbytes    = (size_t)3 * DIM * DIM * sizeof(short);
  const size_t need_base = 3 * elems * sizeof(short) + wbytes;
  short* Wb;
  if (ws_size >= need_base) Wb = VtT + elems;
  else Wb = (short*)((char*)d_out + (size_t)out_size * sizeof(float) - wbytes);
  short* Wqb = Wb;
  short* Wkb = Wb + DIM * DIM;
  short* Wvb = Wb + 2 * DIM * DIM;

  dim3 blk(256, 1, 1);
  dim3 blk512(512, 1, 1);
  wcvt_kernel <<<dim3(96, 1, 1),           blk, 0, stream>>>(Wq, Wk, Wv, Wb);
  proj_kernel <<<dim3(BATCH*SQL/32, 1, 1), blk, 0, stream>>>(query,  Wqb, bq, Qb);
  proj_kernel <<<dim3(BATCH*SKL/32, 1, 1), blk, 0, stream>>>(keys,   Wkb, bk, Kb);
  projV_kernel<<<dim3(BATCH*SKL/32, 1, 1), blk, 0, stream>>>(values, Wvb, bv, VtT);
  // grid 256 = 8 batch x 32 q-tiles (128 q each)
  attn_kernel <<<dim3(256, 1, 1), blk512, 0, stream>>>(Qb, Kb, VtT, out);
}

// Round 16
// 292.478 us; speedup vs baseline: 1.7990x; 1.1028x over previous
//
#include <hip/hip_runtime.h>
#include <hip/hip_bf16.h>
#include <math.h>

#define BATCH 8
#define SQL 4096
#define SKL 4096
#define DIM 256
#define KVB 64
#define NIT (SKL / KVB)

typedef __attribute__((ext_vector_type(8))) short short8;
typedef __attribute__((ext_vector_type(4))) float f32x4;
typedef __attribute__((ext_vector_type(4))) float floatx4;

typedef __attribute__((address_space(3))) unsigned int lds_uint;
typedef __attribute__((address_space(1))) unsigned int glob_uint;

__device__ __forceinline__ void gl_lds16(const void* g, void* l) {
  __builtin_amdgcn_global_load_lds((const glob_uint*)g, (lds_uint*)l, 16, 0, 0);
}

__device__ __forceinline__ short f2bf(float f) {
  union { float f; unsigned u; } x; x.f = f;
  unsigned r = x.u + 0x7fffu + ((x.u >> 16) & 1u);
  return (short)(r >> 16);
}

// Kt rows 512B / Vt rows 128B: slot ^= row&7 (2-way residue, ~free). Pl padded.
__device__ __forceinline__ int swz(int row) { return (row & 7) << 4; }

// max-reduce across a 16-lane DPP row, pure VALU, bit-exact (R12-proven)
__device__ __forceinline__ float dpp_max16(float v) {
  float t;
  t = __int_as_float(__builtin_amdgcn_mov_dpp(__float_as_int(v), 0xB1, 0xF, 0xF, true));  // quad_perm xor1
  v = fmaxf(v, t);
  t = __int_as_float(__builtin_amdgcn_mov_dpp(__float_as_int(v), 0x4E, 0xF, 0xF, true));  // quad_perm xor2
  v = fmaxf(v, t);
  t = __int_as_float(__builtin_amdgcn_mov_dpp(__float_as_int(v), 0x124, 0xF, 0xF, true)); // row_ror:4
  v = fmaxf(v, t);
  t = __int_as_float(__builtin_amdgcn_mov_dpp(__float_as_int(v), 0x128, 0xF, 0xF, true)); // row_ror:8
  v = fmaxf(v, t);
  return v;
}

// ---------- W fp32 -> bf16, once ----------
__global__ __launch_bounds__(256) void wcvt_kernel(
    const float* __restrict__ W0, const float* __restrict__ W1,
    const float* __restrict__ W2, short* __restrict__ out)
{
  const int m = blockIdx.x >> 5;
  const int i = ((blockIdx.x & 31) * 256 + threadIdx.x) * 8;
  const float* W = (m == 0) ? W0 : ((m == 1) ? W1 : W2);
  floatx4 a = *(const floatx4*)(W + i);
  floatx4 c = *(const floatx4*)(W + i + 4);
  short8 v;
  #pragma unroll
  for (int j = 0; j < 4; ++j) { v[j] = f2bf(a[j]); v[j+4] = f2bf(c[j]); }
  *(short8*)(out + (size_t)m * DIM * DIM + i) = v;
}

// ---------- projection, W-RESIDENT: 64 m-rows/block; C = X.W^T + b ----------
// Wave holds its 32 W-frags (8kk x 4nb) in regs across the whole m-loop.
__global__ __launch_bounds__(256, 2) void proj_kernel(
    const float* __restrict__ X, const short* __restrict__ Wb,
    const float* __restrict__ bias, short* __restrict__ out)
{
  const int lane = threadIdx.x & 63;
  const int wave = threadIdx.x >> 6;
  const int lr = lane & 15, hi = lane >> 4;
  const int m0 = blockIdx.x * 64;
  const int n0 = wave * 64;

  short8 wf[8][4];
  #pragma unroll
  for (int kk = 0; kk < 8; ++kk)
    #pragma unroll
    for (int nb = 0; nb < 4; ++nb)
      wf[kk][nb] = *(const short8*)(Wb + (size_t)(n0 + nb*16 + lr) * DIM + kk*32 + hi*8);

  float bv[4];
  #pragma unroll
  for (int nb = 0; nb < 4; ++nb) bv[nb] = bias[n0 + nb*16 + lr];

  #pragma unroll
  for (int ms = 0; ms < 4; ++ms) {
    const float* xrow = X + (size_t)(m0 + ms*16 + lr) * DIM;
    // batch-issue the 16 X loads for this 16-row chunk (one exposed latency)
    floatx4 xv0[8], xv1[8];
    #pragma unroll
    for (int kk = 0; kk < 8; ++kk) {
      xv0[kk] = *(const floatx4*)(xrow + kk*32 + hi*8);
      xv1[kk] = *(const floatx4*)(xrow + kk*32 + hi*8 + 4);
    }
    f32x4 acc[4] = {(f32x4)0.f,(f32x4)0.f,(f32x4)0.f,(f32x4)0.f};
    #pragma unroll
    for (int kk = 0; kk < 8; ++kk) {
      short8 a;
      #pragma unroll
      for (int j = 0; j < 4; ++j) { a[j] = f2bf(xv0[kk][j]); a[j+4] = f2bf(xv1[kk][j]); }
      #pragma unroll
      for (int nb = 0; nb < 4; ++nb)
        acc[nb] = __builtin_amdgcn_mfma_f32_16x16x32_bf16(a, wf[kk][nb], acc[nb], 0, 0, 0);
    }
    #pragma unroll
    for (int nb = 0; nb < 4; ++nb)
      #pragma unroll
      for (int r = 0; r < 4; ++r)
        out[(size_t)(m0 + ms*16 + hi*4 + r) * DIM + n0 + nb*16 + lr] = f2bf(acc[nb][r] + bv[nb]);
  }
}

// ---------- V projection, W-RESIDENT, output TRANSPOSED: outT[b][d][k] ----------
// 64 rows/block = 2 x 32-row transpose chunks.
__global__ __launch_bounds__(256, 2) void projV_kernel(
    const float* __restrict__ X, const short* __restrict__ Wb,
    const float* __restrict__ bias, short* __restrict__ outT)
{
  __shared__ short tile[32][264];
  const int lane = threadIdx.x & 63;
  const int wave = threadIdx.x >> 6;
  const int lr = lane & 15, hi = lane >> 4;
  const int n0 = wave * 64;

  short8 wf[8][4];
  #pragma unroll
  for (int kk = 0; kk < 8; ++kk)
    #pragma unroll
    for (int nb = 0; nb < 4; ++nb)
      wf[kk][nb] = *(const short8*)(Wb + (size_t)(n0 + nb*16 + lr) * DIM + kk*32 + hi*8);

  float bv[4];
  #pragma unroll
  for (int nb = 0; nb < 4; ++nb) bv[nb] = bias[n0 + nb*16 + lr];

  #pragma unroll
  for (int ms = 0; ms < 2; ++ms) {
    const int mbase = blockIdx.x * 64 + ms * 32;

    f32x4 acc0[4] = {(f32x4)0.f,(f32x4)0.f,(f32x4)0.f,(f32x4)0.f};
    f32x4 acc1[4] = {(f32x4)0.f,(f32x4)0.f,(f32x4)0.f,(f32x4)0.f};
    const float* xr0 = X + (size_t)(mbase + lr) * DIM;
    const float* xr1 = X + (size_t)(mbase + 16 + lr) * DIM;

    #pragma unroll
    for (int kk = 0; kk < 8; ++kk) {
      const int k8 = kk * 32 + hi * 8;
      floatx4 xa = *(const floatx4*)(xr0 + k8);
      floatx4 xb = *(const floatx4*)(xr0 + k8 + 4);
      floatx4 ya = *(const floatx4*)(xr1 + k8);
      floatx4 yb = *(const floatx4*)(xr1 + k8 + 4);
      short8 a0, a1;
      #pragma unroll
      for (int j = 0; j < 4; ++j) {
        a0[j] = f2bf(xa[j]); a0[j+4] = f2bf(xb[j]);
        a1[j] = f2bf(ya[j]); a1[j+4] = f2bf(yb[j]);
      }
      #pragma unroll
      for (int nb = 0; nb < 4; ++nb) {
        acc0[nb] = __builtin_amdgcn_mfma_f32_16x16x32_bf16(a0, wf[kk][nb], acc0[nb], 0, 0, 0);
        acc1[nb] = __builtin_amdgcn_mfma_f32_16x16x32_bf16(a1, wf[kk][nb], acc1[nb], 0, 0, 0);
      }
    }
    #pragma unroll
    for (int nb = 0; nb < 4; ++nb) {
      const int n = n0 + nb*16 + lr;
      #pragma unroll
      for (int r = 0; r < 4; ++r) {
        tile[hi*4 + r][n]      = f2bf(acc0[nb][r] + bv[nb]);
        tile[16 + hi*4 + r][n] = f2bf(acc1[nb][r] + bv[nb]);
      }
    }
    __syncthreads();
    const int t = threadIdx.x;
    short8 v0, v1, v2, v3;
    #pragma unroll
    for (int k = 0; k < 8; ++k) {
      v0[k] = tile[k][t]; v1[k] = tile[k+8][t];
      v2[k] = tile[k+16][t]; v3[k] = tile[k+24][t];
    }
    const int b  = mbase >> 12;
    const int k0 = mbase & (SKL - 1);
    short* p = outT + (size_t)b * DIM * SKL + (size_t)t * SKL + k0;
    *(short8*)(p)      = v0;
    *(short8*)(p + 8)  = v1;
    *(short8*)(p + 16) = v2;
    *(short8*)(p + 24) = v3;
    __syncthreads();   // protect tile before next ms overwrites it
  }
}

// ---------- flash attention: R12 VERBATIM (proven 229 us, absmax 0.05859375) ----------
__global__ __launch_bounds__(512, 1) void attn_kernel(
    const short* __restrict__ Qb, const short* __restrict__ Kb,
    const short* __restrict__ VtG, float* __restrict__ out)
{
  __shared__ alignas(16) short Kt[2][64][256];   // 64 KB, 512B rows, XOR swz
  __shared__ alignas(16) short Vt[2][256][64];   // 64 KB, 128B rows, XOR swz
  __shared__ alignas(16) short Pl[8][16][72];    // 18 KB, 144B rows (padded, no XOR)

  const int tid  = threadIdx.x;
  const int lane = tid & 63;
  const int wave = tid >> 6;                     // 0..7
  const int lr = lane & 15, hi = lane >> 4;

  const int b     = blockIdx.x & 7;     // batch -> XCD pinning (grid=256)
  const int qtile = blockIdx.x >> 3;
  const int q0w   = qtile * 128 + wave * 16;

  const short* Qp = Qb  + ((size_t)b * SQL + q0w) * DIM;
  const short* Kp = Kb  + (size_t)b * SKL * DIM;
  const short* Vp = VtG + (size_t)b * DIM * SKL;

  short8 qf[8];
  #pragma unroll
  for (int kk = 0; kk < 8; ++kk)
    qf[kk] = *(const short8*)(Qp + (size_t)lr * DIM + kk*32 + hi*8);

  f32x4 o[16];
  #pragma unroll
  for (int i = 0; i < 16; ++i) o[i] = (f32x4)0.f;
  float mr[4]   = {-3.0e38f,-3.0e38f,-3.0e38f,-3.0e38f};
  float lacc[4] = {0.f,0.f,0.f,0.f};

  auto stage = [&](int buf, int kv) {
    #pragma unroll
    for (int i = 0; i < 4; ++i) {              // K: 64 rows x 512B
      const int row0 = wave*8 + i*2;
      const int row  = row0 + (lane >> 5);
      const int colb = ((lane & 31) * 16) ^ swz(row);
      gl_lds16((const char*)(Kp + (size_t)(kv + row) * DIM) + colb, (void*)&Kt[buf][row0][0]);
    }
    #pragma unroll
    for (int i = 0; i < 4; ++i) {              // V^T: 256 rows x 128B
      const int d0 = wave*32 + i*8;
      const int d  = d0 + (lane >> 3);
      const int colb = ((lane & 7) * 16) ^ swz(d);
      gl_lds16((const char*)(Vp + (size_t)d * SKL + kv) + colb, (void*)&Vt[buf][d0][0]);
    }
  };

  stage(0, 0);
  __syncthreads();
  int cur = 0;

  const char* plw = (const char*)&Pl[wave][0][0];

  for (int it = 0; it < NIT; ++it) {
    if (it + 1 < NIT) stage(cur ^ 1, (it + 1) * KVB);

    // ---- QK^T: S[16q][64k] ----
    const char* ktb = (const char*)&Kt[cur][0][0];
    f32x4 s[4];
    #pragma unroll
    for (int ks = 0; ks < 4; ++ks) s[ks] = (f32x4)0.f;
    __builtin_amdgcn_s_setprio(1);
    #pragma unroll
    for (int kk = 0; kk < 8; ++kk) {
      #pragma unroll
      for (int ks = 0; ks < 4; ++ks) {
        const int row = ks*16 + lr;
        short8 kf = *(const short8*)(ktb + row*512 + (((kk*64) + hi*16) ^ swz(row)));
        s[ks] = __builtin_amdgcn_mfma_f32_16x16x32_bf16(qf[kk], kf, s[ks], 0, 0, 0);
      }
    }
    __builtin_amdgcn_s_setprio(0);

    // ---- EXACT online softmax (row = hi*4+r, col = ks*16+lr), DPP max-reduce ----
    #pragma unroll
    for (int r = 0; r < 4; ++r) {
      float mx = dpp_max16(fmaxf(fmaxf(s[0][r], s[1][r]), fmaxf(s[2][r], s[3][r])));
      if (mx > mr[r]) {                        // bit-exact skip of sc==1.0 rescale
        const float sc = __expf(mr[r] - mx);   // first iter: exp(-inf)=0
        mr[r] = mx;
        lacc[r] *= sc;
        #pragma unroll
        for (int dt = 0; dt < 16; ++dt) o[dt][r] *= sc;
      }
      const int row = hi*4 + r;
      #pragma unroll
      for (int ks = 0; ks < 4; ++ks) {
        const float p = __expf(s[ks][r] - mr[r]);   // <= 1
        lacc[r] += p;
        *(short*)(plw + row*144 + 2*(ks*16 + lr)) = f2bf(p);
      }
    }

    // ---- PV: O[16q][256d] += P[16q][64k] . V[64k][256d] ----
    const char* vtb = (const char*)&Vt[cur][0][0];
    short8 pa[2];
    #pragma unroll
    for (int kh = 0; kh < 2; ++kh)
      pa[kh] = *(const short8*)(plw + lr*144 + kh*64 + hi*16);
    __builtin_amdgcn_s_setprio(1);
    #pragma unroll
    for (int dt = 0; dt < 16; ++dt) {
      #pragma unroll
      for (int kh = 0; kh < 2; ++kh) {
        const int d = dt*16 + lr;
        short8 vf = *(const short8*)(vtb + d*128 + ((kh*64 + hi*16) ^ swz(d)));
        o[dt] = __builtin_amdgcn_mfma_f32_16x16x32_bf16(pa[kh], vf, o[dt], 0, 0, 0);
      }
    }
    __builtin_amdgcn_s_setprio(0);

    __syncthreads();
    cur ^= 1;
  }

  // ---- epilogue: one cross-lane reduce of l, normalize, store ----
  float lsum[4];
  #pragma unroll
  for (int r = 0; r < 4; ++r) lsum[r] = lacc[r];
  #pragma unroll
  for (int off = 8; off >= 1; off >>= 1)
    #pragma unroll
    for (int r = 0; r < 4; ++r)
      lsum[r] += __shfl_xor(lsum[r], off, 64);

  float* op = out + ((size_t)b * SQL + q0w) * DIM;
  #pragma unroll
  for (int r = 0; r < 4; ++r) {
    const float inv = 1.0f / lsum[r];
    #pragma unroll
    for (int dt = 0; dt < 16; ++dt)
      op[(size_t)(hi*4 + r) * DIM + dt*16 + lr] = o[dt][r] * inv;
  }
}

extern "C" void kernel_launch(void* const* d_in, const int* in_sizes, int n_in,
                              void* d_out, int out_size, void* d_ws, size_t ws_size,
                              hipStream_t stream) {
  const float* query  = (const float*)d_in[0];
  const float* keys   = (const float*)d_in[1];
  const float* values = (const float*)d_in[2];
  const float* Wq = (const float*)d_in[3];
  const float* bq = (const float*)d_in[4];
  const float* Wk = (const float*)d_in[5];
  const float* bk = (const float*)d_in[6];
  const float* Wv = (const float*)d_in[7];
  const float* bv = (const float*)d_in[8];
  float* out = (float*)d_out;

  const size_t elems = (size_t)BATCH * SQL * DIM;
  short* Qb  = (short*)d_ws;
  short* Kb  = Qb + elems;
  short* VtT = Kb + elems;

  const size_t wbytes    = (size_t)3 * DIM * DIM * sizeof(short);
  const size_t need_base = 3 * elems * sizeof(short) + wbytes;
  short* Wb;
  if (ws_size >= need_base) Wb = VtT + elems;
  else Wb = (short*)((char*)d_out + (size_t)out_size * sizeof(float) - wbytes);
  short* Wqb = Wb;
  short* Wkb = Wb + DIM * DIM;
  short* Wvb = Wb + 2 * DIM * DIM;

  dim3 blk(256, 1, 1);
  dim3 blk512(512, 1, 1);
  wcvt_kernel <<<dim3(96, 1, 1),            blk, 0, stream>>>(Wq, Wk, Wv, Wb);
  proj_kernel <<<dim3(BATCH*SQL/64, 1, 1),  blk, 0, stream>>>(query,  Wqb, bq, Qb);
  proj_kernel <<<dim3(BATCH*SKL/64, 1, 1),  blk, 0, stream>>>(keys,   Wkb, bk, Kb);
  projV_kernel<<<dim3(BATCH*SKL/64, 1, 1),  blk, 0, stream>>>(values, Wvb, bv, VtT);
  attn_kernel <<<dim3(BATCH*SQL/128, 1, 1), blk512, 0, stream>>>(Qb, Kb, VtT, out);
}